// Round 3
// baseline (515.576 us; speedup 1.0000x reference)
//
#include <hip/hip_runtime.h>
#include <hip/hip_bf16.h>
#include <stdint.h>

#define B_    1024
#define N_    64
#define F_    1024
#define H1_   256
#define H2_   128
#define NC_   128
#define ALPHA 0.2f
#define BN_EPS 1e-5f

typedef __attribute__((ext_vector_type(4))) float  f32x4;
typedef __attribute__((ext_vector_type(8))) __bf16 bf16x8;
typedef __attribute__((ext_vector_type(4))) __bf16 bf16x4;

__device__ inline float sign_ref(float v) {
    // matches v / max(|v|, 1e-12): exact +-1 for |v| >= 1e-12
    float s = copysignf(1.0f, v);
    return (fabsf(v) >= 1e-12f) ? s : v * 1e12f;
}

__device__ __forceinline__ void gload_lds16(const void* g, void* l) {
    auto gp = reinterpret_cast<const __attribute__((address_space(1))) void*>(
        reinterpret_cast<uintptr_t>(g));
    auto lp = reinterpret_cast<__attribute__((address_space(3))) void*>(
        reinterpret_cast<uintptr_t>(l));
    __builtin_amdgcn_global_load_lds(gp, lp, 16, 0, 0);
}

__device__ inline float blk_reduce(float v, float* buf) {
    #pragma unroll
    for (int o = 32; o > 0; o >>= 1) v += __shfl_xor(v, o, 64);
    __syncthreads();
    const int wave = threadIdx.x >> 6, lane = threadIdx.x & 63;
    if (lane == 0) buf[wave] = v;
    __syncthreads();
    float r = 0.f;
    if (threadIdx.x == 0) {
        const int nw = blockDim.x >> 6;
        for (int i = 0; i < nw; ++i) r += buf[i];
    }
    return r;  // valid on thread 0 only
}

// ---------------------------------------------------------------------------
// Prep: W1,W2 -> bf16; w1a=W1^T a11; w2a=W2^T a21; w2a22=W2^T a22;
// c1=b1.a11, c2=b2.a21, c2p=b2.a22.   grid: 294 x 256
// ---------------------------------------------------------------------------
__global__ __launch_bounds__(256) void k_prep(
    const float* __restrict__ W1, const float* __restrict__ W2,
    const float* __restrict__ b1, const float* __restrict__ a11,
    const float* __restrict__ a12, const float* __restrict__ b2,
    const float* __restrict__ a21, const float* __restrict__ a22,
    __bf16* __restrict__ W1b, __bf16* __restrict__ W2b,
    float* __restrict__ w1a, float* __restrict__ w2a,
    float* __restrict__ w2a22, float* __restrict__ cscal)
{
    __shared__ float rbuf[8];
    const int blk = blockIdx.x, tid = threadIdx.x;
    if (blk < 256) {                       // W1 -> bf16
        const int i0 = blk * 1024 + tid * 4;
        float4 v = *(const float4*)(W1 + i0);
        bf16x4 p = { (__bf16)v.x, (__bf16)v.y, (__bf16)v.z, (__bf16)v.w };
        *(bf16x4*)(W1b + i0) = p;
    } else if (blk < 288) {                // W2 -> bf16
        const int i0 = (blk - 256) * 1024 + tid * 4;
        float4 v = *(const float4*)(W2 + i0);
        bf16x4 p = { (__bf16)v.x, (__bf16)v.y, (__bf16)v.z, (__bf16)v.w };
        *(bf16x4*)(W2b + i0) = p;
    } else if (blk < 292) {                // W1^T a11
        const int f = (blk - 288) * 256 + tid;
        float s1 = 0.f;
        #pragma unroll 8
        for (int h = 0; h < H1_; ++h) s1 += W1[h * F_ + f] * a11[h];
        w1a[f] = s1;
    } else if (blk == 292) {               // W2^T {a21,a22}
        float s1 = 0.f, s2 = 0.f;
        #pragma unroll 8
        for (int h = 0; h < H2_; ++h) {
            const float w = W2[h * H1_ + tid];
            s1 += w * a21[h]; s2 += w * a22[h];
        }
        w2a[tid] = s1; w2a22[tid] = s2;
    } else {                               // scalars
        float v1 = b1[tid] * a11[tid];
        float v2 = (tid < H2_) ? b2[tid] * a21[tid] : 0.f;
        float v3 = (tid < H2_) ? b2[tid] * a22[tid] : 0.f;
        float r1 = blk_reduce(v1, rbuf);
        float r2 = blk_reduce(v2, rbuf);
        float r3 = blk_reduce(v3, rbuf);
        if (tid == 0) { cscal[0] = r1; cscal[1] = r2; cscal[2] = r3; }
    }
}

// ---------------------------------------------------------------------------
// GEMM1 + fused layer-1 front: nbh1[128 x 256] = sign(A) @ W1b^T + b1 (bf16),
// then per 64-row half (= one sample b): score1 -> softmax -> out1 ->
// per-b BN(alpha,beta) -> BN1 partials -> spart2 precompute.
// grid: 512 x 256 (each block owns b = 2*blockIdx.x + {0,1})
// ---------------------------------------------------------------------------
__global__ __launch_bounds__(256, 1) void k_gemm1(
    const float* __restrict__ A, const __bf16* __restrict__ Bw,
    const float* __restrict__ bias, __bf16* __restrict__ C,
    const float* __restrict__ x, const float* __restrict__ w1a,
    const float* __restrict__ a12, const float* __restrict__ w2a22,
    const float* __restrict__ cscal, const float* __restrict__ g1p,
    const float* __restrict__ be1p,
    float* __restrict__ out1, float* __restrict__ alpha1,
    float* __restrict__ beta1, float* __restrict__ psum1,
    float* __restrict__ psq1, float* __restrict__ spart)
{
    constexpr int BM = 128, BN = 256, BK = 64, K = F_;
    constexpr int LDA = BK + 8;
    __shared__ __attribute__((aligned(16))) char smem[BM * LDA * 2 + BN * BK * 2];
    __bf16* As = (__bf16*)smem;                    // [BM][LDA], padded
    __bf16* Bs = (__bf16*)(smem + BM * LDA * 2);   // [BN*BK], swizzled 16B chunks
    __bf16* Cs = Bs;                               // reused in epilogue: [64][256]
    __shared__ float a12s[H1_];
    __shared__ float w2a22s[H1_];
    __shared__ float sv[N_];
    __shared__ float rbuf[8];
    __shared__ float fscal[4];   // 0,1: sself1 for halves; 2: alpha; 3: beta

    const int tid = threadIdx.x;
    const int wave = tid >> 6, lane = tid & 63;
    const int wm = wave & 1, wn = wave >> 1;
    const int rowin = lane & 15, kq = lane >> 4;
    const size_t m0 = (size_t)blockIdx.x * BM;
    const size_t b0 = (size_t)blockIdx.x * 2;

    // ---- sself1 for both halves + weight vectors to LDS ----
    {
        const float* xb = x + b0 * F_;
        float p0 = 0.f, p1 = 0.f;
        #pragma unroll
        for (int i = 0; i < 4; ++i) {
            const float wa = w1a[tid + i * 256];
            p0 += sign_ref(xb[tid + i * 256]) * wa;
            p1 += sign_ref(xb[F_ + tid + i * 256]) * wa;
        }
        a12s[tid] = a12[tid]; w2a22s[tid] = w2a22[tid];
        float r0 = blk_reduce(p0, rbuf);
        float r1 = blk_reduce(p1, rbuf);
        if (tid == 0) {
            const float c1 = cscal[0];
            fscal[0] = r0 + c1; fscal[1] = r1 + c1;
        }
    }

    f32x4 acc[4][8] = {};

    const int cqA = tid & 15, r0A = tid >> 4;
    const float* Abase = A + m0 * K + cqA * 4;

    for (int k0 = 0; k0 < K; k0 += BK) {
        // async global->LDS stage of B chunks (swizzled: slot (r,c8) holds
        // global chunk (r, c8 ^ (r&7)))
        #pragma unroll
        for (int it = 0; it < 8; ++it) {
            const int s = it * 256 + tid;
            const int r = s >> 3;
            const int c8 = (s & 7) ^ (r & 7);
            gload_lds16(Bw + (size_t)r * K + k0 + c8 * 8, Bs + s * 8);
        }
        // stage A with sign transform (fp32 -> +-1 bf16)
        #pragma unroll
        for (int rr = 0; rr < 8; ++rr) {
            const int r = r0A + rr * 16;
            float4 v = *(const float4*)(Abase + (size_t)r * K + k0);
            bf16x4 p = { (__bf16)sign_ref(v.x), (__bf16)sign_ref(v.y),
                         (__bf16)sign_ref(v.z), (__bf16)sign_ref(v.w) };
            *(bf16x4*)&As[r * LDA + cqA * 4] = p;
        }
        __syncthreads();
        #pragma unroll
        for (int ks = 0; ks < 2; ++ks) {
            bf16x8 af[4], bv[8];
            #pragma unroll
            for (int mi = 0; mi < 4; ++mi)
                af[mi] = *(const bf16x8*)&As[(wm * 64 + mi * 16 + rowin) * LDA + ks * 32 + kq * 8];
            #pragma unroll
            for (int ni = 0; ni < 8; ++ni) {
                const int r = wn * 128 + ni * 16 + rowin;
                const int c = (ks * 4 + kq) ^ (r & 7);
                bv[ni] = *(const bf16x8*)&Bs[(r * 8 + c) * 8];
            }
            #pragma unroll
            for (int mi = 0; mi < 4; ++mi)
                #pragma unroll
                for (int ni = 0; ni < 8; ++ni)
                    acc[mi][ni] = __builtin_amdgcn_mfma_f32_16x16x32_bf16(
                        af[mi], bv[ni], acc[mi][ni], 0, 0, 0);
        }
        __syncthreads();
    }
    // epilogue per 64-row half: +bias, cvt bf16, store, then fused front
    const int cr0 = (lane >> 4) * 4, cc = lane & 15;
    for (int half = 0; half < 2; ++half) {
        if (wm == half) {
            #pragma unroll
            for (int ni = 0; ni < 8; ++ni) {
                const int col = wn * 128 + ni * 16 + cc;
                const float bs = bias[col];
                #pragma unroll
                for (int mi = 0; mi < 4; ++mi)
                    #pragma unroll
                    for (int i = 0; i < 4; ++i)
                        Cs[(mi * 16 + cr0 + i) * 256 + col] =
                            (__bf16)(acc[mi][ni][i] + bs);
            }
        }
        __syncthreads();
        #pragma unroll
        for (int it = 0; it < 8; ++it) {
            const int s = it * 256 + tid;                  // 16B chunk id
            const size_t row = m0 + half * 64 + (s >> 5);
            *(bf16x8*)(C + row * 256 + (s & 31) * 8) = *(const bf16x8*)&Cs[s * 8];
        }
        __syncthreads();

        // ================= fused front for b = b0 + half =================
        const size_t b = b0 + half;
        {   // score1 -> leaky
            const int n = tid >> 2, q = tid & 3;
            float p = 0.f;
            for (int i = 0; i < 64; ++i) {
                const int h = q * 64 + ((i + tid) & 63);   // stagger banks
                p += (float)Cs[n * 256 + h] * a12s[h];
            }
            p += __shfl_xor(p, 1); p += __shfl_xor(p, 2);
            if (q == 0) { float s = fscal[half] + p; sv[n] = s > 0.f ? s : ALPHA * s; }
        }
        __syncthreads();
        if (tid < 64) {    // softmax over neighbors
            float s = sv[tid], m = s;
            #pragma unroll
            for (int o = 1; o < 64; o <<= 1) m = fmaxf(m, __shfl_xor(m, o));
            float e = __expf(s - m), t = e;
            #pragma unroll
            for (int o = 1; o < 64; o <<= 1) t += __shfl_xor(t, o);
            sv[tid] = e / t;
        }
        __syncthreads();
        // out1, per-b neighbor BN stats, BN1 partials
        float o1 = 0.f, ss = 0.f, sq = 0.f;
        for (int n2 = 0; n2 < N_; ++n2) {
            const float v = (float)Cs[n2 * 256 + tid];
            o1 += sv[n2] * v; ss += v; sq += v * v;
        }
        out1[b * H1_ + tid] = o1;
        {
            const float rs = blk_reduce(ss, rbuf);
            const float rq = blk_reduce(sq, rbuf);
            if (tid == 0) {
                const float inv = 1.f / (float)(N_ * H1_);
                const float mean = rs * inv, var = rq * inv - mean * mean;
                const float a = (*g1p) * rsqrtf(var + BN_EPS);
                const float bb = (*be1p) - a * mean;
                alpha1[b] = a; beta1[b] = bb;
                fscal[2] = a; fscal[3] = bb;
            }
            const float rsx = blk_reduce(o1, rbuf);
            const float rqx = blk_reduce(o1 * o1, rbuf);
            if (tid == 0) { psum1[b] = rsx; psq1[b] = rqx; }
        }
        __syncthreads();   // fscal[2],[3] visible
        {   // spart2[b][n] = sum_h relu(al*v+be) * w2a22[h]
            const float al_ = fscal[2], be_ = fscal[3];
            const int n = tid >> 2, q = tid & 3;
            float p = 0.f;
            for (int i = 0; i < 64; ++i) {
                const int h = q * 64 + ((i + tid) & 63);
                const float v = (float)Cs[n * 256 + h];
                p += fmaxf(fmaf(al_, v, be_), 0.f) * w2a22s[h];
            }
            p += __shfl_xor(p, 1); p += __shfl_xor(p, 2);
            if (q == 0) spart[b * N_ + n] = p;
        }
        __syncthreads();   // before half=1 overwrites Cs
    }
}

// ---------------------------------------------------------------------------
// Back fused: global BN1 (redundant 4 KB reduce) + sself2 + score2 (from
// precomputed spart) + softmax + combo + out2 GEMV + BN2 partials.
// grid: 1024 x 256
// ---------------------------------------------------------------------------
__global__ __launch_bounds__(256) void k_back(
    const __bf16* __restrict__ nbh1, const float* __restrict__ out1,
    const float* __restrict__ alpha1, const float* __restrict__ beta1,
    const float* __restrict__ psum1, const float* __restrict__ psq1,
    const float* __restrict__ g1p, const float* __restrict__ be1p,
    const float* __restrict__ w2a, const float* __restrict__ spart,
    const float* __restrict__ cscal, const __bf16* __restrict__ W2b,
    const float* __restrict__ b2,
    float* __restrict__ out2, float* __restrict__ psum2,
    float* __restrict__ psq2)
{
    __shared__ __attribute__((aligned(16))) __bf16 tile[N_ * H1_];  // 32 KB
    __shared__ float w2as[H1_];
    __shared__ float sv[N_];
    __shared__ float g2s[H1_ + 8];    // swizzled: k stored at k + (k>>5)
    __shared__ float hpart[H2_];
    __shared__ float rbuf[8];
    __shared__ float scal[3];         // 0:ax1 1:bx1 2:sself2+c2+c2p

    const int b = blockIdx.x, tid = threadIdx.x;

    // issue tile loads first so they overlap the reductions
    const __bf16* src = nbh1 + (size_t)b * N_ * H1_;
    #pragma unroll
    for (int it = 0; it < 8; ++it)
        gload_lds16(src + (it * 256 + tid) * 8, tile + (it * 256 + tid) * 8);
    w2as[tid] = w2a[tid];
    const float o1 = out1[(size_t)b * H1_ + tid];
    const float al = alpha1[b], be = beta1[b];

    // ---- global BN1 from partials ----
    {
        float s = 0.f, q = 0.f;
        for (int i = tid; i < B_; i += 256) { s += psum1[i]; q += psq1[i]; }
        const float gs = blk_reduce(s, rbuf);
        const float gq = blk_reduce(q, rbuf);
        if (tid == 0) {
            const float n = (float)(B_ * H1_);
            const float mean = gs / n, var = gq / n - mean * mean;
            const float a = (*g1p) * rsqrtf(var + BN_EPS);
            scal[0] = a; scal[1] = (*be1p) - a * mean;
        }
    }
    __syncthreads();   // scal + tile ready

    // ---- sself2 (fold in c2 and c2p) ----
    {
        const float x2 = fmaxf(fmaf(scal[0], o1, scal[1]), 0.f);
        const float r = blk_reduce(x2 * w2as[tid], rbuf);
        if (tid == 0) scal[2] = r + cscal[1] + cscal[2];
    }
    __syncthreads();

    // ---- score2 (precomputed spart) -> leaky -> softmax ----
    if (tid < 64) {
        float s = scal[2] + spart[(size_t)b * N_ + tid];
        s = s > 0.f ? s : ALPHA * s;
        float m = s;
        #pragma unroll
        for (int o = 1; o < 64; o <<= 1) m = fmaxf(m, __shfl_xor(m, o));
        float e = __expf(s - m), t = e;
        #pragma unroll
        for (int o = 1; o < 64; o <<= 1) t += __shfl_xor(t, o);
        sv[tid] = e / t;
    }
    __syncthreads();

    // ---- weighted combo over neighbors ----
    {
        float g = 0.f;
        for (int n2 = 0; n2 < N_; ++n2) {
            const float v = (float)tile[n2 * H1_ + tid];
            g += sv[n2] * fmaxf(fmaf(al, v, be), 0.f);
        }
        g2s[tid + (tid >> 5)] = g;
    }
    __syncthreads();

    // ---- out2 = g2 @ W2^T + b2, plus out2 stats ----
    #pragma unroll 4
    for (int j = 0; j < 16; ++j) {
        const int idx = j * 256 + tid;       // bf16x8 chunk of W2b
        const int h = idx >> 5, k8 = idx & 31;
        const bf16x8 w = ((const bf16x8*)W2b)[idx];
        float p = 0.f;
        #pragma unroll
        for (int i = 0; i < 8; ++i) {
            const int k = k8 * 8 + i;
            p += (float)w[i] * g2s[k + (k >> 5)];
        }
        p += __shfl_xor(p, 1); p += __shfl_xor(p, 2); p += __shfl_xor(p, 4);
        p += __shfl_xor(p, 8); p += __shfl_xor(p, 16);
        if ((tid & 31) == 0) hpart[h] = p;
    }
    __syncthreads();
    {
        float o2 = 0.f;
        if (tid < H2_) o2 = hpart[tid] + b2[tid];
        const float rs2 = blk_reduce(o2, rbuf);
        const float rq2 = blk_reduce(o2 * o2, rbuf);
        if (tid < H2_) out2[(size_t)b * H2_ + tid] = o2;
        if (tid == 0) { psum2[b] = rs2; psq2[b] = rq2; }
    }
}

// ---------------------------------------------------------------------------
// Final: global BN2 (redundant reduce) + ReLU + Linear.  grid: 1024 x 128
// ---------------------------------------------------------------------------
__global__ __launch_bounds__(128) void k_fin(
    const float* __restrict__ out2, const float* __restrict__ psum2,
    const float* __restrict__ psq2, const float* __restrict__ g2p,
    const float* __restrict__ be2p, const float* __restrict__ Wl,
    const float* __restrict__ bl, float* __restrict__ logits)
{
    __shared__ float xr[H2_];
    __shared__ float Ws[NC_][H2_ + 1];
    __shared__ float axbx[2];
    __shared__ float rbuf[8];
    const int b = blockIdx.x, tid = threadIdx.x;
    {
        float s = 0.f, q = 0.f;
        for (int i = tid; i < B_; i += 128) { s += psum2[i]; q += psq2[i]; }
        const float gs = blk_reduce(s, rbuf);
        const float gq = blk_reduce(q, rbuf);
        if (tid == 0) {
            const float n = (float)(B_ * H2_);
            const float mean = gs / n, var = gq / n - mean * mean;
            const float a = (*g2p) * rsqrtf(var + BN_EPS);
            axbx[0] = a; axbx[1] = (*be2p) - a * mean;
        }
    }
    for (int i = tid; i < NC_ * H2_ / 4; i += 128) {
        float4 v = ((const float4*)Wl)[i];
        const int r = i >> 5, c = (i & 31) * 4;
        Ws[r][c] = v.x; Ws[r][c + 1] = v.y; Ws[r][c + 2] = v.z; Ws[r][c + 3] = v.w;
    }
    __syncthreads();
    xr[tid] = fmaxf(fmaf(axbx[0], out2[(size_t)b * H2_ + tid], axbx[1]), 0.f);
    __syncthreads();
    float acc = bl[tid];
    #pragma unroll 4
    for (int h = 0; h < H2_; ++h) acc += xr[h] * Ws[tid][h];
    logits[(size_t)b * NC_ + tid] = acc;
}

// ---------------------------------------------------------------------------
extern "C" void kernel_launch(void* const* d_in, const int* in_sizes, int n_in,
                              void* d_out, int out_size, void* d_ws, size_t ws_size,
                              hipStream_t stream)
{
    const float* x   = (const float*)d_in[0];
    const float* nb  = (const float*)d_in[1];
    const float* W1  = (const float*)d_in[2];
    const float* b1  = (const float*)d_in[3];
    const float* a11 = (const float*)d_in[4];
    const float* a12 = (const float*)d_in[5];
    const float* g1  = (const float*)d_in[6];
    const float* be1 = (const float*)d_in[7];
    const float* W2  = (const float*)d_in[8];
    const float* b2  = (const float*)d_in[9];
    const float* a21 = (const float*)d_in[10];
    const float* a22 = (const float*)d_in[11];
    const float* g2  = (const float*)d_in[12];
    const float* be2 = (const float*)d_in[13];
    const float* Wl  = (const float*)d_in[14];
    const float* bl  = (const float*)d_in[15];
    float* logits = (float*)d_out;

    size_t off = 0;
    auto alc = [&](size_t bytes) {
        void* p = (char*)d_ws + off;
        off = (off + bytes + 255) & ~(size_t)255;
        return p;
    };
    __bf16* W1b   = (__bf16*)alc((size_t)H1_ * F_ * 2);
    __bf16* W2b   = (__bf16*)alc((size_t)H2_ * H1_ * 2);
    float* w1a    = (float*)alc(F_ * 4);
    float* w2a    = (float*)alc(H1_ * 4);
    float* w2a22  = (float*)alc(H1_ * 4);
    float* cscal  = (float*)alc(3 * 4);
    float* alpha1 = (float*)alc(B_ * 4);
    float* beta1  = (float*)alc(B_ * 4);
    float* psum1  = (float*)alc(B_ * 4);
    float* psq1   = (float*)alc(B_ * 4);
    float* psum2  = (float*)alc(B_ * 4);
    float* psq2   = (float*)alc(B_ * 4);
    float* spart  = (float*)alc((size_t)B_ * N_ * 4);
    float* out1   = (float*)alc((size_t)B_ * H1_ * 4);
    float* out2   = (float*)alc((size_t)B_ * H2_ * 4);
    __bf16* nbh1  = (__bf16*)alc((size_t)B_ * N_ * H1_ * 2);   // 32 MiB

    k_prep<<<294, 256, 0, stream>>>(W1, W2, b1, a11, a12, b2, a21, a22,
                                    W1b, W2b, w1a, w2a, w2a22, cscal);
    k_gemm1<<<(B_ * N_) / 128, 256, 0, stream>>>(
        nb, W1b, b1, nbh1, x, w1a, a12, w2a22, cscal, g1, be1,
        out1, alpha1, beta1, psum1, psq1, spart);
    k_back<<<B_, 256, 0, stream>>>(nbh1, out1, alpha1, beta1, psum1, psq1,
                                   g1, be1, w2a, spart, cscal, W2b, b2,
                                   out2, psum2, psq2);
    k_fin<<<B_, 128, 0, stream>>>(out2, psum2, psq2, g2, be2, Wl, bl, logits);
}

// Round 4
// 467.649 us; speedup vs baseline: 1.1025x; 1.1025x over previous
//
#include <hip/hip_runtime.h>
#include <hip/hip_bf16.h>
#include <stdint.h>

#define B_    1024
#define N_    64
#define F_    1024
#define H1_   256
#define H2_   128
#define NC_   128
#define ALPHA 0.2f
#define BN_EPS 1e-5f

typedef __attribute__((ext_vector_type(4))) float  f32x4;
typedef __attribute__((ext_vector_type(8))) __bf16 bf16x8;
typedef __attribute__((ext_vector_type(4))) __bf16 bf16x4;

__device__ inline float sign_ref(float v) {
    // matches v / max(|v|, 1e-12): exact +-1 for |v| >= 1e-12
    float s = copysignf(1.0f, v);
    return (fabsf(v) >= 1e-12f) ? s : v * 1e12f;
}

__device__ __forceinline__ void gload_lds16(const void* g, void* l) {
    auto gp = reinterpret_cast<const __attribute__((address_space(1))) void*>(
        reinterpret_cast<uintptr_t>(g));
    auto lp = reinterpret_cast<__attribute__((address_space(3))) void*>(
        reinterpret_cast<uintptr_t>(l));
    __builtin_amdgcn_global_load_lds(gp, lp, 16, 0, 0);
}

__device__ inline float blk_reduce(float v, float* buf) {
    #pragma unroll
    for (int o = 32; o > 0; o >>= 1) v += __shfl_xor(v, o, 64);
    __syncthreads();
    const int wave = threadIdx.x >> 6, lane = threadIdx.x & 63;
    if (lane == 0) buf[wave] = v;
    __syncthreads();
    float r = 0.f;
    if (threadIdx.x == 0) {
        const int nw = blockDim.x >> 6;
        for (int i = 0; i < nw; ++i) r += buf[i];
    }
    return r;  // valid on thread 0 only
}

// ---------------------------------------------------------------------------
// Prep: W1,W2 -> bf16; w1a=W1^T a11; w2a=W2^T a21; w2a22=W2^T a22;
// c1=b1.a11, c2=b2.a21, c2p=b2.a22.   grid: 294 x 256
// ---------------------------------------------------------------------------
__global__ __launch_bounds__(256) void k_prep(
    const float* __restrict__ W1, const float* __restrict__ W2,
    const float* __restrict__ b1, const float* __restrict__ a11,
    const float* __restrict__ a12, const float* __restrict__ b2,
    const float* __restrict__ a21, const float* __restrict__ a22,
    __bf16* __restrict__ W1b, __bf16* __restrict__ W2b,
    float* __restrict__ w1a, float* __restrict__ w2a,
    float* __restrict__ w2a22, float* __restrict__ cscal)
{
    __shared__ float rbuf[8];
    const int blk = blockIdx.x, tid = threadIdx.x;
    if (blk < 256) {                       // W1 -> bf16
        const int i0 = blk * 1024 + tid * 4;
        float4 v = *(const float4*)(W1 + i0);
        bf16x4 p = { (__bf16)v.x, (__bf16)v.y, (__bf16)v.z, (__bf16)v.w };
        *(bf16x4*)(W1b + i0) = p;
    } else if (blk < 288) {                // W2 -> bf16
        const int i0 = (blk - 256) * 1024 + tid * 4;
        float4 v = *(const float4*)(W2 + i0);
        bf16x4 p = { (__bf16)v.x, (__bf16)v.y, (__bf16)v.z, (__bf16)v.w };
        *(bf16x4*)(W2b + i0) = p;
    } else if (blk < 292) {                // W1^T a11
        const int f = (blk - 288) * 256 + tid;
        float s1 = 0.f;
        #pragma unroll 8
        for (int h = 0; h < H1_; ++h) s1 += W1[h * F_ + f] * a11[h];
        w1a[f] = s1;
    } else if (blk == 292) {               // W2^T {a21,a22}
        float s1 = 0.f, s2 = 0.f;
        #pragma unroll 8
        for (int h = 0; h < H2_; ++h) {
            const float w = W2[h * H1_ + tid];
            s1 += w * a21[h]; s2 += w * a22[h];
        }
        w2a[tid] = s1; w2a22[tid] = s2;
    } else {                               // scalars
        float v1 = b1[tid] * a11[tid];
        float v2 = (tid < H2_) ? b2[tid] * a21[tid] : 0.f;
        float v3 = (tid < H2_) ? b2[tid] * a22[tid] : 0.f;
        float r1 = blk_reduce(v1, rbuf);
        float r2 = blk_reduce(v2, rbuf);
        float r3 = blk_reduce(v3, rbuf);
        if (tid == 0) { cscal[0] = r1; cscal[1] = r2; cscal[2] = r3; }
    }
}

// ---------------------------------------------------------------------------
// GEMM1 + fused layer-1 front, one sample per block (BM=64):
// nbh1[b] = sign(A_b) @ W1b^T + b1 (bf16), then score1 -> softmax -> out1 ->
// per-b BN(alpha,beta) -> BN1 partials -> spart2 precompute.
// grid: 1024 x 256.  acc 4x4 (64 AGPR) so >=2 waves/SIMD fit.
// ---------------------------------------------------------------------------
__global__ __launch_bounds__(256, 2) void k_gemm1(
    const float* __restrict__ A, const __bf16* __restrict__ Bw,
    const float* __restrict__ bias, __bf16* __restrict__ C,
    const float* __restrict__ x, const float* __restrict__ w1a,
    const float* __restrict__ a12, const float* __restrict__ w2a22,
    const float* __restrict__ cscal, const float* __restrict__ g1p,
    const float* __restrict__ be1p,
    float* __restrict__ out1, float* __restrict__ alpha1,
    float* __restrict__ beta1, float* __restrict__ psum1,
    float* __restrict__ psq1, float* __restrict__ spart)
{
    constexpr int BM = 64, BK = 64, K = F_;
    constexpr int LDA = BK + 8;
    __shared__ __attribute__((aligned(16))) char smem[BM * LDA * 2 + 256 * BK * 2];
    __bf16* As = (__bf16*)smem;                    // [64][LDA], padded
    __bf16* Bs = (__bf16*)(smem + BM * LDA * 2);   // [256*64], swizzled 16B chunks
    __bf16* Cs = Bs;                               // epilogue reuse: [64][256]
    __shared__ float a12s[H1_];
    __shared__ float w2a22s[H1_];
    __shared__ float sv[N_];
    __shared__ float rbuf[8];
    __shared__ float fscal[4];   // 0: sself1; 2: alpha; 3: beta

    const int tid = threadIdx.x;
    const int wave = tid >> 6, lane = tid & 63;
    const int rowin = lane & 15, kq = lane >> 4;
    const size_t b = blockIdx.x;

    // ---- sself1 + weight vectors to LDS ----
    {
        const float* xb = x + b * F_;
        float p0 = 0.f;
        #pragma unroll
        for (int i = 0; i < 4; ++i)
            p0 += sign_ref(xb[tid + i * 256]) * w1a[tid + i * 256];
        a12s[tid] = a12[tid]; w2a22s[tid] = w2a22[tid];
        float r0 = blk_reduce(p0, rbuf);
        if (tid == 0) fscal[0] = r0 + cscal[0];
    }

    f32x4 acc[4][4] = {};

    const int cqA = tid & 15, r0A = tid >> 4;
    const float* Abase = A + b * (size_t)BM * K + cqA * 4;

    for (int k0 = 0; k0 < K; k0 += BK) {
        // async global->LDS stage of B chunks (swizzled: slot (r,c8) holds
        // global chunk (r, c8 ^ (r&7)))
        #pragma unroll
        for (int it = 0; it < 8; ++it) {
            const int s = it * 256 + tid;
            const int r = s >> 3;
            const int c8 = (s & 7) ^ (r & 7);
            gload_lds16(Bw + (size_t)r * K + k0 + c8 * 8, Bs + s * 8);
        }
        // stage A with sign transform (fp32 -> +-1 bf16), 4 rows/thread
        #pragma unroll
        for (int rr = 0; rr < 4; ++rr) {
            const int r = r0A + rr * 16;
            float4 v = *(const float4*)(Abase + (size_t)r * K + k0);
            bf16x4 p = { (__bf16)sign_ref(v.x), (__bf16)sign_ref(v.y),
                         (__bf16)sign_ref(v.z), (__bf16)sign_ref(v.w) };
            *(bf16x4*)&As[r * LDA + cqA * 4] = p;
        }
        __syncthreads();
        #pragma unroll
        for (int ks = 0; ks < 2; ++ks) {
            bf16x8 af[4], bv[4];
            #pragma unroll
            for (int mi = 0; mi < 4; ++mi)
                af[mi] = *(const bf16x8*)&As[(mi * 16 + rowin) * LDA + ks * 32 + kq * 8];
            #pragma unroll
            for (int ni = 0; ni < 4; ++ni) {
                const int r = wave * 64 + ni * 16 + rowin;
                const int c = (ks * 4 + kq) ^ (r & 7);
                bv[ni] = *(const bf16x8*)&Bs[(r * 8 + c) * 8];
            }
            #pragma unroll
            for (int mi = 0; mi < 4; ++mi)
                #pragma unroll
                for (int ni = 0; ni < 4; ++ni)
                    acc[mi][ni] = __builtin_amdgcn_mfma_f32_16x16x32_bf16(
                        af[mi], bv[ni], acc[mi][ni], 0, 0, 0);
        }
        __syncthreads();
    }

    // ---- epilogue: +bias, cvt bf16 into Cs (wave wn owns 64 cols) ----
    const int cr0 = (lane >> 4) * 4, cc = lane & 15;
    #pragma unroll
    for (int ni = 0; ni < 4; ++ni) {
        const int col = wave * 64 + ni * 16 + cc;
        const float bs = bias[col];
        #pragma unroll
        for (int mi = 0; mi < 4; ++mi)
            #pragma unroll
            for (int i = 0; i < 4; ++i)
                Cs[(mi * 16 + cr0 + i) * 256 + col] = (__bf16)(acc[mi][ni][i] + bs);
    }
    __syncthreads();
    // coalesced nbh1 store + score1 in the same phase
    #pragma unroll
    for (int it = 0; it < 8; ++it) {
        const int s = it * 256 + tid;                  // 16B chunk id
        *(bf16x8*)(C + (b * 64 + (s >> 5)) * 256 + (s & 31) * 8) =
            *(const bf16x8*)&Cs[s * 8];
    }
    {   // score1 -> leaky
        const int n = tid >> 2, q = tid & 3;
        float p = 0.f;
        for (int i = 0; i < 64; ++i) {
            const int h = q * 64 + ((i + tid) & 63);   // stagger banks
            p += (float)Cs[n * 256 + h] * a12s[h];
        }
        p += __shfl_xor(p, 1); p += __shfl_xor(p, 2);
        if (q == 0) { float s = fscal[0] + p; sv[n] = s > 0.f ? s : ALPHA * s; }
    }
    __syncthreads();
    if (tid < 64) {    // softmax over neighbors
        float s = sv[tid], m = s;
        #pragma unroll
        for (int o = 1; o < 64; o <<= 1) m = fmaxf(m, __shfl_xor(m, o));
        float e = __expf(s - m), t = e;
        #pragma unroll
        for (int o = 1; o < 64; o <<= 1) t += __shfl_xor(t, o);
        sv[tid] = e / t;
    }
    __syncthreads();
    // out1, per-b neighbor BN stats, BN1 partials
    float o1 = 0.f, ss = 0.f, sq = 0.f;
    for (int n2 = 0; n2 < N_; ++n2) {
        const float v = (float)Cs[n2 * 256 + tid];
        o1 += sv[n2] * v; ss += v; sq += v * v;
    }
    out1[b * H1_ + tid] = o1;
    {
        const float rs = blk_reduce(ss, rbuf);
        const float rq = blk_reduce(sq, rbuf);
        if (tid == 0) {
            const float inv = 1.f / (float)(N_ * H1_);
            const float mean = rs * inv, var = rq * inv - mean * mean;
            const float a = (*g1p) * rsqrtf(var + BN_EPS);
            const float bb = (*be1p) - a * mean;
            alpha1[b] = a; beta1[b] = bb;
            fscal[2] = a; fscal[3] = bb;
        }
        const float rsx = blk_reduce(o1, rbuf);
        const float rqx = blk_reduce(o1 * o1, rbuf);
        if (tid == 0) { psum1[b] = rsx; psq1[b] = rqx; }
    }
    __syncthreads();   // fscal[2],[3] visible
    {   // spart2[b][n] = sum_h relu(al*v+be) * w2a22[h]
        const float al_ = fscal[2], be_ = fscal[3];
        const int n = tid >> 2, q = tid & 3;
        float p = 0.f;
        for (int i = 0; i < 64; ++i) {
            const int h = q * 64 + ((i + tid) & 63);
            const float v = (float)Cs[n * 256 + h];
            p += fmaxf(fmaf(al_, v, be_), 0.f) * w2a22s[h];
        }
        p += __shfl_xor(p, 1); p += __shfl_xor(p, 2);
        if (q == 0) spart[b * N_ + n] = p;
    }
}

// ---------------------------------------------------------------------------
// Back fused: global BN1 (redundant 4 KB reduce) + sself2 + score2 (from
// precomputed spart) + softmax + combo + out2 GEMV + BN2 partials.
// grid: 1024 x 256
// ---------------------------------------------------------------------------
__global__ __launch_bounds__(256) void k_back(
    const __bf16* __restrict__ nbh1, const float* __restrict__ out1,
    const float* __restrict__ alpha1, const float* __restrict__ beta1,
    const float* __restrict__ psum1, const float* __restrict__ psq1,
    const float* __restrict__ g1p, const float* __restrict__ be1p,
    const float* __restrict__ w2a, const float* __restrict__ spart,
    const float* __restrict__ cscal, const __bf16* __restrict__ W2b,
    const float* __restrict__ b2,
    float* __restrict__ out2, float* __restrict__ psum2,
    float* __restrict__ psq2)
{
    __shared__ __attribute__((aligned(16))) __bf16 tile[N_ * H1_];  // 32 KB
    __shared__ float w2as[H1_];
    __shared__ float sv[N_];
    __shared__ float g2s[H1_ + 8];    // swizzled: k stored at k + (k>>5)
    __shared__ float hpart[H2_];
    __shared__ float rbuf[8];
    __shared__ float scal[3];         // 0:ax1 1:bx1 2:sself2+c2+c2p

    const int b = blockIdx.x, tid = threadIdx.x;

    // issue tile loads first so they overlap the reductions
    const __bf16* src = nbh1 + (size_t)b * N_ * H1_;
    #pragma unroll
    for (int it = 0; it < 8; ++it)
        gload_lds16(src + (it * 256 + tid) * 8, tile + (it * 256 + tid) * 8);
    w2as[tid] = w2a[tid];
    const float o1 = out1[(size_t)b * H1_ + tid];
    const float al = alpha1[b], be = beta1[b];

    // ---- global BN1 from partials ----
    {
        float s = 0.f, q = 0.f;
        for (int i = tid; i < B_; i += 256) { s += psum1[i]; q += psq1[i]; }
        const float gs = blk_reduce(s, rbuf);
        const float gq = blk_reduce(q, rbuf);
        if (tid == 0) {
            const float n = (float)(B_ * H1_);
            const float mean = gs / n, var = gq / n - mean * mean;
            const float a = (*g1p) * rsqrtf(var + BN_EPS);
            scal[0] = a; scal[1] = (*be1p) - a * mean;
        }
    }
    __syncthreads();   // scal + tile ready

    // ---- sself2 (fold in c2 and c2p) ----
    {
        const float x2 = fmaxf(fmaf(scal[0], o1, scal[1]), 0.f);
        const float r = blk_reduce(x2 * w2as[tid], rbuf);
        if (tid == 0) scal[2] = r + cscal[1] + cscal[2];
    }
    __syncthreads();

    // ---- score2 (precomputed spart) -> leaky -> softmax ----
    if (tid < 64) {
        float s = scal[2] + spart[(size_t)b * N_ + tid];
        s = s > 0.f ? s : ALPHA * s;
        float m = s;
        #pragma unroll
        for (int o = 1; o < 64; o <<= 1) m = fmaxf(m, __shfl_xor(m, o));
        float e = __expf(s - m), t = e;
        #pragma unroll
        for (int o = 1; o < 64; o <<= 1) t += __shfl_xor(t, o);
        sv[tid] = e / t;
    }
    __syncthreads();

    // ---- weighted combo over neighbors ----
    {
        float g = 0.f;
        for (int n2 = 0; n2 < N_; ++n2) {
            const float v = (float)tile[n2 * H1_ + tid];
            g += sv[n2] * fmaxf(fmaf(al, v, be), 0.f);
        }
        g2s[tid + (tid >> 5)] = g;
    }
    __syncthreads();

    // ---- out2 = g2 @ W2^T + b2, plus out2 stats ----
    #pragma unroll 4
    for (int j = 0; j < 16; ++j) {
        const int idx = j * 256 + tid;       // bf16x8 chunk of W2b
        const int h = idx >> 5, k8 = idx & 31;
        const bf16x8 w = ((const bf16x8*)W2b)[idx];
        float p = 0.f;
        #pragma unroll
        for (int i = 0; i < 8; ++i) {
            const int k = k8 * 8 + i;
            p += (float)w[i] * g2s[k + (k >> 5)];
        }
        p += __shfl_xor(p, 1); p += __shfl_xor(p, 2); p += __shfl_xor(p, 4);
        p += __shfl_xor(p, 8); p += __shfl_xor(p, 16);
        if ((tid & 31) == 0) hpart[h] = p;
    }
    __syncthreads();
    {
        float o2 = 0.f;
        if (tid < H2_) o2 = hpart[tid] + b2[tid];
        const float rs2 = blk_reduce(o2, rbuf);
        const float rq2 = blk_reduce(o2 * o2, rbuf);
        if (tid < H2_) out2[(size_t)b * H2_ + tid] = o2;
        if (tid == 0) { psum2[b] = rs2; psq2[b] = rq2; }
    }
}

// ---------------------------------------------------------------------------
// Final: global BN2 (redundant reduce) + ReLU + Linear.  grid: 1024 x 128
// ---------------------------------------------------------------------------
__global__ __launch_bounds__(128) void k_fin(
    const float* __restrict__ out2, const float* __restrict__ psum2,
    const float* __restrict__ psq2, const float* __restrict__ g2p,
    const float* __restrict__ be2p, const float* __restrict__ Wl,
    const float* __restrict__ bl, float* __restrict__ logits)
{
    __shared__ float xr[H2_];
    __shared__ float Ws[NC_][H2_ + 1];
    __shared__ float axbx[2];
    __shared__ float rbuf[8];
    const int b = blockIdx.x, tid = threadIdx.x;
    {
        float s = 0.f, q = 0.f;
        for (int i = tid; i < B_; i += 128) { s += psum2[i]; q += psq2[i]; }
        const float gs = blk_reduce(s, rbuf);
        const float gq = blk_reduce(q, rbuf);
        if (tid == 0) {
            const float n = (float)(B_ * H2_);
            const float mean = gs / n, var = gq / n - mean * mean;
            const float a = (*g2p) * rsqrtf(var + BN_EPS);
            axbx[0] = a; axbx[1] = (*be2p) - a * mean;
        }
    }
    for (int i = tid; i < NC_ * H2_ / 4; i += 128) {
        float4 v = ((const float4*)Wl)[i];
        const int r = i >> 5, c = (i & 31) * 4;
        Ws[r][c] = v.x; Ws[r][c + 1] = v.y; Ws[r][c + 2] = v.z; Ws[r][c + 3] = v.w;
    }
    __syncthreads();
    xr[tid] = fmaxf(fmaf(axbx[0], out2[(size_t)b * H2_ + tid], axbx[1]), 0.f);
    __syncthreads();
    float acc = bl[tid];
    #pragma unroll 4
    for (int h = 0; h < H2_; ++h) acc += xr[h] * Ws[tid][h];
    logits[(size_t)b * NC_ + tid] = acc;
}

// ---------------------------------------------------------------------------
extern "C" void kernel_launch(void* const* d_in, const int* in_sizes, int n_in,
                              void* d_out, int out_size, void* d_ws, size_t ws_size,
                              hipStream_t stream)
{
    const float* x   = (const float*)d_in[0];
    const float* nb  = (const float*)d_in[1];
    const float* W1  = (const float*)d_in[2];
    const float* b1  = (const float*)d_in[3];
    const float* a11 = (const float*)d_in[4];
    const float* a12 = (const float*)d_in[5];
    const float* g1  = (const float*)d_in[6];
    const float* be1 = (const float*)d_in[7];
    const float* W2  = (const float*)d_in[8];
    const float* b2  = (const float*)d_in[9];
    const float* a21 = (const float*)d_in[10];
    const float* a22 = (const float*)d_in[11];
    const float* g2  = (const float*)d_in[12];
    const float* be2 = (const float*)d_in[13];
    const float* Wl  = (const float*)d_in[14];
    const float* bl  = (const float*)d_in[15];
    float* logits = (float*)d_out;

    size_t off = 0;
    auto alc = [&](size_t bytes) {
        void* p = (char*)d_ws + off;
        off = (off + bytes + 255) & ~(size_t)255;
        return p;
    };
    __bf16* W1b   = (__bf16*)alc((size_t)H1_ * F_ * 2);
    __bf16* W2b   = (__bf16*)alc((size_t)H2_ * H1_ * 2);
    float* w1a    = (float*)alc(F_ * 4);
    float* w2a    = (float*)alc(H1_ * 4);
    float* w2a22  = (float*)alc(H1_ * 4);
    float* cscal  = (float*)alc(3 * 4);
    float* alpha1 = (float*)alc(B_ * 4);
    float* beta1  = (float*)alc(B_ * 4);
    float* psum1  = (float*)alc(B_ * 4);
    float* psq1   = (float*)alc(B_ * 4);
    float* psum2  = (float*)alc(B_ * 4);
    float* psq2   = (float*)alc(B_ * 4);
    float* spart  = (float*)alc((size_t)B_ * N_ * 4);
    float* out1   = (float*)alc((size_t)B_ * H1_ * 4);
    float* out2   = (float*)alc((size_t)B_ * H2_ * 4);
    __bf16* nbh1  = (__bf16*)alc((size_t)B_ * N_ * H1_ * 2);   // 32 MiB

    k_prep<<<294, 256, 0, stream>>>(W1, W2, b1, a11, a12, b2, a21, a22,
                                    W1b, W2b, w1a, w2a, w2a22, cscal);
    k_gemm1<<<B_, 256, 0, stream>>>(
        nb, W1b, b1, nbh1, x, w1a, a12, w2a22, cscal, g1, be1,
        out1, alpha1, beta1, psum1, psq1, spart);
    k_back<<<B_, 256, 0, stream>>>(nbh1, out1, alpha1, beta1, psum1, psq1,
                                   g1, be1, w2a, spart, cscal, W2b, b2,
                                   out2, psum2, psq2);
    k_fin<<<B_, 128, 0, stream>>>(out2, psum2, psq2, g2, be2, Wl, bl, logits);
}